// Round 5
// baseline (309.307 us; speedup 1.0000x reference)
//
#include <hip/hip_runtime.h>
#include <hip/hip_cooperative_groups.h>
#include <stdint.h>

namespace cg = cooperative_groups;

// N=4 batches, C=256, S=16, H*W=1024, K1=S*C=4096, 3 layers.
#define CC   256
#define SSL  16
#define NB   4
#define HWP  1024
#define K1   4096
#define EPSV 1e-5f
#define GRID 256   // 1 block/CU -> cooperative co-residency is trivially satisfiable

typedef __attribute__((ext_vector_type(8))) short bf16x8;
typedef __attribute__((ext_vector_type(4))) float f32x4;

__device__ __forceinline__ ushort f2bf(float f) {
    uint32_t u = __float_as_uint(f);
    uint32_t r = (u + 0x7FFFu + ((u >> 16) & 1u)) >> 16;   // RNE
    return (ushort)r;
}

#define SMEM_BYTES 67584   // max over phases: msst 256*65*4 + 16*64 flags

// ---------------------------------------------------------------------------
// Phase A (depth-1 prep), job-stride over 1088 jobs:
//   [0,64)     msst with self-computed flags (heavy jobs first for balance)
//   [64,320)   feats [n][c][p] fp32 -> fT [n][p][c] bf16 (LDS transpose)
//   [320,1088) conv_w fp32 -> bf16 copy
__device__ __forceinline__ void phase_prep(char* smem, const float* adj,
                                           const float* feats, const float* conv_w,
                                           ushort* fT, ushort* wb, ushort* msst) {
    const int t = threadIdx.x;
    for (int job = blockIdx.x; job < 1088; job += GRID) {
        __syncthreads();                  // LDS reuse across jobs
        if (job < 64) {                   // ---- msst (self-flags) ----
            float (*Mc)[65] = (float(*)[65])smem;        // [256][65] fp32
            uint8_t* fl = (uint8_t*)(smem + 66560);      // [16][64]
            const int n = job >> 4, at = (job >> 2) & 3, bt = job & 3;
            const float* m = adj + (size_t)n * CC * CC + bt * 64;
#pragma unroll
            for (int it = 0; it < 16; ++it) {
                const int r = it * 16 + (t >> 4), c = (t & 15) * 4;
                *(float4*)&Mc[r][c] = *(const float4*)(m + (size_t)r * CC + c);
            }
            __syncthreads();
#pragma unroll
            for (int e = 0; e < 4; ++e) {
                const int pair = t + e * 256;
                const int k = pair >> 6, b = pair & 63;
                bool allp = true, anyp = false;
#pragma unroll
                for (int i = 0; i < 16; ++i) {
                    const bool p = Mc[k * 16 + i][b] > 0.0f;
                    allp = allp && p;
                    anyp = anyp || p;
                }
                fl[k * 64 + b] = allp ? (uint8_t)2 : (anyp ? (uint8_t)1 : (uint8_t)0);
            }
            __syncthreads();
            const int b = t >> 2, a0 = at * 64 + (t & 3) * 16;
            ushort bx[16], bp[16];
#pragma unroll
            for (int e = 0; e < 16; ++e) {
                const float x = Mc[a0 + e][b];
                bx[e] = f2bf(x);
                bp[e] = f2bf(fmaxf(x, 0.0f));
            }
            ushort* dst = msst + ((size_t)(n * CC + bt * 64 + b)) * K1 + a0;
#pragma unroll
            for (int k = 0; k < 16; ++k) {
                const uint8_t f = fl[k * 64 + b];
                ushort* dk = dst + k * CC;
#pragma unroll
                for (int a4 = 0; a4 < 4; ++a4) {
                    ushort4 o;
                    o.x = (f == 2) ? bx[a4 * 4 + 0] : ((f == 1) ? bp[a4 * 4 + 0] : (ushort)0);
                    o.y = (f == 2) ? bx[a4 * 4 + 1] : ((f == 1) ? bp[a4 * 4 + 1] : (ushort)0);
                    o.z = (f == 2) ? bx[a4 * 4 + 2] : ((f == 1) ? bp[a4 * 4 + 2] : (ushort)0);
                    o.w = (f == 2) ? bx[a4 * 4 + 3] : ((f == 1) ? bp[a4 * 4 + 3] : (ushort)0);
                    *(ushort4*)(dk + a4 * 4) = o;
                }
            }
        } else if (job < 320) {           // ---- featsT ----
            float (*Ts)[68] = (float(*)[68])smem;
            const int f = job - 64;
            const int n = f >> 6, r = f & 63;
            const int c0 = (r >> 4) * 64, p0 = (r & 15) * 64;
            const float* src = feats + ((size_t)n * CC + c0) * HWP + p0;
            const int cr = t >> 2, pq = (t & 3) * 16;
#pragma unroll
            for (int i = 0; i < 4; ++i)
                *(float4*)&Ts[cr][pq + i * 4] = *(const float4*)(src + (size_t)cr * HWP + pq + i * 4);
            __syncthreads();
            const int pl = t >> 2, cc0 = (t & 3) * 16;
            ushort* dst = fT + ((size_t)n * HWP + p0 + pl) * CC + c0 + cc0;
#pragma unroll
            for (int a4 = 0; a4 < 4; ++a4) {
                ushort4 o;
                o.x = f2bf(Ts[cc0 + a4 * 4 + 0][pl]);
                o.y = f2bf(Ts[cc0 + a4 * 4 + 1][pl]);
                o.z = f2bf(Ts[cc0 + a4 * 4 + 2][pl]);
                o.w = f2bf(Ts[cc0 + a4 * 4 + 3][pl]);
                *(ushort4*)(dst + a4 * 4) = o;
            }
        } else {                          // ---- convw bf16 ----
            const int c = job - 320;
            const int idx = (c * 256 + t) * 16;
#pragma unroll
            for (int i = 0; i < 4; ++i) {
                float4 v = *(const float4*)(conv_w + idx + i * 4);
                ushort4 o = {f2bf(v.x), f2bf(v.y), f2bf(v.z), f2bf(v.w)};
                *(ushort4*)(wb + idx + i * 4) = o;
            }
        }
    }
}

// ---------------------------------------------------------------------------
// Phase B: W_eff partial GEMM, R2 config. 384 tile-jobs (4 tiles x 12 ln x 8 sp),
// 128x128 tile, BK=32, 4 waves x (4x4) 16x16x32 MFMA. Partials stored [b][o]
// so each lane emits contiguous float4.
__device__ __forceinline__ void phase_weff(char* smem, const ushort* Aw,
                                           const ushort* Bm, float* wpart) {
    ushort (*Al)[40] = (ushort(*)[40])smem;            // [128][40] (+8 pad)
    ushort (*Bl)[40] = (ushort(*)[40])(smem + 10240);
    const int t = threadIdx.x;
    const int wv = t >> 6, L = t & 63;
    const int wr = (wv >> 1) * 64, wc = (wv & 1) * 64;
    const int l16 = L & 15, q = L >> 4;
    const int r0 = t >> 2, kq0 = (t & 3) * 8;
    for (int x = blockIdx.x; x < 384; x += GRID) {
        const int tile = x & 3, ln = (x >> 2) % 12, sp = x / 48;
        const int l = ln >> 2, n = ln & 3;
        const int trow = (tile >> 1) * 128, tcol = (tile & 1) * 128;
        const ushort* A = Aw + (size_t)l * CC * K1;
        const ushort* B = Bm + (size_t)n * CC * K1;
        f32x4 acc[4][4];
#pragma unroll
        for (int i = 0; i < 4; ++i)
#pragma unroll
            for (int j = 0; j < 4; ++j)
                acc[i][j] = (f32x4){0.f, 0.f, 0.f, 0.f};

        const int kbase = sp * 512;
        for (int kt = 0; kt < 16; ++kt) {
            const int kk = kbase + kt * 32;
            int4 a0 = *(const int4*)(A + (size_t)(trow + r0) * K1 + kk + kq0);
            int4 a1 = *(const int4*)(A + (size_t)(trow + 64 + r0) * K1 + kk + kq0);
            int4 b0 = *(const int4*)(B + (size_t)(tcol + r0) * K1 + kk + kq0);
            int4 b1 = *(const int4*)(B + (size_t)(tcol + 64 + r0) * K1 + kk + kq0);
            __syncthreads();
            *(int4*)&Al[r0][kq0] = a0;
            *(int4*)&Al[64 + r0][kq0] = a1;
            *(int4*)&Bl[r0][kq0] = b0;
            *(int4*)&Bl[64 + r0][kq0] = b1;
            __syncthreads();
            bf16x8 af[4], bfr[4];
#pragma unroll
            for (int i = 0; i < 4; ++i)
                af[i] = *(const bf16x8*)&Al[wr + i * 16 + l16][q * 8];
#pragma unroll
            for (int j = 0; j < 4; ++j)
                bfr[j] = *(const bf16x8*)&Bl[wc + j * 16 + l16][q * 8];
#pragma unroll
            for (int i = 0; i < 4; ++i)
#pragma unroll
                for (int j = 0; j < 4; ++j)
                    acc[i][j] = __builtin_amdgcn_mfma_f32_16x16x32_bf16(af[i], bfr[j], acc[i][j], 0, 0, 0);
        }

        float* W = wpart + ((size_t)sp * 12 + ln) * (CC * CC);
#pragma unroll
        for (int i = 0; i < 4; ++i)
#pragma unroll
            for (int j = 0; j < 4; ++j) {
                const int ob = trow + wr + i * 16 + q * 4;   // 4 consecutive o
                const int b  = tcol + wc + j * 16 + l16;
                *(float4*)(W + (size_t)b * CC + ob) =
                    (float4){acc[i][j][0], acc[i][j][1], acc[i][j][2], acc[i][j][3]};
            }
    }
}

// ---------------------------------------------------------------------------
// Phase C: sum 8 partials ([b][o]), fold BN row-scale(o), LDS-transpose,
// emit bf16 Ws[ln][o][b] coalesced. 192 jobs (16 tiles x 12 ln).
__device__ __forceinline__ void phase_reduce(char* smem, const float* wpart,
                                             const float* gamma, const float* var,
                                             ushort* Ws) {
    if (blockIdx.x < 192) {
        ushort (*T)[72] = (ushort(*)[72])smem;
        float* scv = (float*)(smem + 9216);
        const int ln = blockIdx.x >> 4, tile = blockIdx.x & 15;
        const int l = ln >> 2;
        const int bt = tile >> 2, ot = tile & 3;
        const int t = threadIdx.x;
        if (t < 64) {
            const int o = ot * 64 + t;
            scv[t] = gamma[l * CC + o] * rsqrtf(var[l * CC + o] + EPSV);
        }
        __syncthreads();
        const int bl = t >> 2, oc = (t & 3) * 16;
        const float* base = wpart + (size_t)ln * (CC * CC) + (size_t)(bt * 64 + bl) * CC + ot * 64 + oc;
        float s[16] = {};
#pragma unroll
        for (int sp = 0; sp < 8; ++sp) {
            const float* p = base + (size_t)sp * 12 * CC * CC;
#pragma unroll
            for (int c = 0; c < 4; ++c) {
                float4 v = *(const float4*)(p + c * 4);
                s[c * 4 + 0] += v.x; s[c * 4 + 1] += v.y;
                s[c * 4 + 2] += v.z; s[c * 4 + 3] += v.w;
            }
        }
#pragma unroll
        for (int e = 0; e < 16; ++e)
            T[oc + e][bl] = f2bf(s[e] * scv[oc + e]);
        __syncthreads();
        const int ol = t >> 2, b0 = (t & 3) * 16;
        ushort* dst = Ws + ((size_t)ln * CC + ot * 64 + ol) * CC + bt * 64 + b0;
#pragma unroll
        for (int c = 0; c < 4; ++c) {
            ushort4 o = {T[ol][b0 + c * 4 + 0], T[ol][b0 + c * 4 + 1],
                         T[ol][b0 + c * 4 + 2], T[ol][b0 + c * 4 + 3]};
            *(ushort4*)(dst + c * 4) = o;
        }
    }
}

// ---------------------------------------------------------------------------
// Phase D/E/F: layer GEMM (TN): yT[p][o] = sum_b xT[p][b]*Ws[o][b]; epilogue
// relu(acc+bias2[o]); fp32 out[n][o][p] + bf16 xT[p][o] (null for last layer).
// 64x64 tile, 4 waves x (2x2), register prefetch. 256 jobs (64 tiles x 4 n).
__device__ __forceinline__ void phase_layer(char* smem, const ushort* xT,
                                            const ushort* Wsl, const float* convb_l,
                                            const float* gamma_l, const float* beta_l,
                                            const float* mean_l, const float* var_l,
                                            float* outl, ushort* xTn) {
    ushort (*Al)[40] = (ushort(*)[40])smem;
    ushort (*Bl)[40] = (ushort(*)[40])(smem + 5120);
    const int bid = blockIdx.x;
    if (bid < 256) {
        const int n = bid >> 6, tile = bid & 63;
        const int pt = tile & 15, ot = tile >> 4;
        const ushort* Axt = xT + (size_t)n * HWP * CC + (size_t)pt * 64 * CC;
        const ushort* Bw  = Wsl + (size_t)n * CC * CC + (size_t)ot * 64 * CC;
        const int t = threadIdx.x;
        const int wv = t >> 6, L = t & 63;
        const int wr = (wv >> 1) * 32, wc = (wv & 1) * 32;
        const int l16 = L & 15, q = L >> 4;
        const int r0 = t >> 2, kq0 = (t & 3) * 8;
        f32x4 acc[2][2];
#pragma unroll
        for (int i = 0; i < 2; ++i)
#pragma unroll
            for (int j = 0; j < 2; ++j)
                acc[i][j] = (f32x4){0.f, 0.f, 0.f, 0.f};

        int4 av = *(const int4*)(Axt + (size_t)r0 * CC + kq0);
        int4 bv = *(const int4*)(Bw + (size_t)r0 * CC + kq0);
        for (int kt = 0; kt < 8; ++kt) {
            __syncthreads();
            *(int4*)&Al[r0][kq0] = av;
            *(int4*)&Bl[r0][kq0] = bv;
            __syncthreads();
            if (kt < 7) {
                const int kk = (kt + 1) * 32;
                av = *(const int4*)(Axt + (size_t)r0 * CC + kk + kq0);
                bv = *(const int4*)(Bw + (size_t)r0 * CC + kk + kq0);
            }
            bf16x8 af[2], bfr[2];
#pragma unroll
            for (int i = 0; i < 2; ++i)
                af[i] = *(const bf16x8*)&Al[wr + i * 16 + l16][q * 8];
#pragma unroll
            for (int j = 0; j < 2; ++j)
                bfr[j] = *(const bf16x8*)&Bl[wc + j * 16 + l16][q * 8];
#pragma unroll
            for (int i = 0; i < 2; ++i)
#pragma unroll
                for (int j = 0; j < 2; ++j)
                    acc[i][j] = __builtin_amdgcn_mfma_f32_16x16x32_bf16(af[i], bfr[j], acc[i][j], 0, 0, 0);
        }

        float* outn = outl + (size_t)n * CC * HWP;
        ushort* xtn = xTn ? xTn + (size_t)n * HWP * CC : (ushort*)0;
#pragma unroll
        for (int i = 0; i < 2; ++i)
#pragma unroll
            for (int j = 0; j < 2; ++j) {
                const int p = pt * 64 + wr + i * 16 + q * 4;   // D row
                const int o = ot * 64 + wc + j * 16 + l16;     // D col
                const float sc = gamma_l[o] * rsqrtf(var_l[o] + EPSV);
                const float b2 = sc * (convb_l[o] - mean_l[o]) + beta_l[o];
                float v0 = fmaxf(acc[i][j][0] + b2, 0.f);
                float v1 = fmaxf(acc[i][j][1] + b2, 0.f);
                float v2 = fmaxf(acc[i][j][2] + b2, 0.f);
                float v3 = fmaxf(acc[i][j][3] + b2, 0.f);
                *(float4*)(outn + (size_t)o * HWP + p) = (float4){v0, v1, v2, v3};
                if (xtn) {
                    xtn[(size_t)(p + 0) * CC + o] = f2bf(v0);
                    xtn[(size_t)(p + 1) * CC + o] = f2bf(v1);
                    xtn[(size_t)(p + 2) * CC + o] = f2bf(v2);
                    xtn[(size_t)(p + 3) * CC + o] = f2bf(v3);
                }
            }
    }
}

// ---------------------------------------------------------------------------
// Cooperative mega-kernel: all phases, grid.sync() between (device-scope fence).
__global__ __launch_bounds__(256, 2) void mega_kernel(
    const float* __restrict__ adj, const float* __restrict__ feats,
    const float* __restrict__ conv_w, const float* __restrict__ conv_b,
    const float* __restrict__ gamma, const float* __restrict__ beta,
    const float* __restrict__ mean, const float* __restrict__ var,
    float* __restrict__ out, ushort* fT0, ushort* convwb, ushort* msst,
    float* wpart, ushort* Wsb, ushort* xT1, ushort* xT2) {
    __shared__ __align__(16) char smem[SMEM_BYTES];
    cg::grid_group grid = cg::this_grid();
    phase_prep(smem, adj, feats, conv_w, fT0, convwb, msst);
    __syncthreads(); grid.sync();
    phase_weff(smem, convwb, msst, wpart);
    __syncthreads(); grid.sync();
    phase_reduce(smem, wpart, gamma, var, Wsb);
    __syncthreads(); grid.sync();
    phase_layer(smem, fT0, Wsb, conv_b, gamma, beta, mean, var, out, xT1);
    __syncthreads(); grid.sync();
    phase_layer(smem, xT1, Wsb + 4 * CC * CC, conv_b + CC, gamma + CC, beta + CC,
                mean + CC, var + CC, out + (size_t)NB * CC * HWP, xT2);
    __syncthreads(); grid.sync();
    phase_layer(smem, xT2, Wsb + 8 * CC * CC, conv_b + 2 * CC, gamma + 2 * CC,
                beta + 2 * CC, mean + 2 * CC, var + 2 * CC,
                out + (size_t)2 * NB * CC * HWP, (ushort*)0);
}

// ---- Fallback wrappers (same phase bodies, plain launches, same GRID) ------
__global__ __launch_bounds__(256, 2) void prep_k(const float* adj, const float* feats,
                                                 const float* conv_w, ushort* fT,
                                                 ushort* wb, ushort* msst) {
    __shared__ __align__(16) char smem[SMEM_BYTES];
    phase_prep(smem, adj, feats, conv_w, fT, wb, msst);
}
__global__ __launch_bounds__(256, 2) void weff_k(const ushort* Aw, const ushort* Bm,
                                                 float* wpart) {
    __shared__ __align__(16) char smem[SMEM_BYTES];
    phase_weff(smem, Aw, Bm, wpart);
}
__global__ __launch_bounds__(256, 2) void reduce_k(const float* wpart, const float* gamma,
                                                   const float* var, ushort* Ws) {
    __shared__ __align__(16) char smem[SMEM_BYTES];
    phase_reduce(smem, wpart, gamma, var, Ws);
}
__global__ __launch_bounds__(256, 2) void layer_k(const ushort* xT, const ushort* Wsl,
                                                  const float* convb_l, const float* gamma_l,
                                                  const float* beta_l, const float* mean_l,
                                                  const float* var_l, float* outl,
                                                  ushort* xTn) {
    __shared__ __align__(16) char smem[SMEM_BYTES];
    phase_layer(smem, xT, Wsl, convb_l, gamma_l, beta_l, mean_l, var_l, outl, xTn);
}

// ---------------------------------------------------------------------------
extern "C" void kernel_launch(void* const* d_in, const int* in_sizes, int n_in,
                              void* d_out, int out_size, void* d_ws, size_t ws_size,
                              hipStream_t stream) {
    const float* adj    = (const float*)d_in[1];
    const float* feats  = (const float*)d_in[0];
    const float* conv_w = (const float*)d_in[2];
    const float* conv_b = (const float*)d_in[3];
    const float* gamma  = (const float*)d_in[4];
    const float* beta   = (const float*)d_in[5];
    const float* mean   = (const float*)d_in[6];
    const float* var    = (const float*)d_in[7];
    float* out = (float*)d_out;

    // ws layout (bytes): convwb 6MB | msst 8MB | Ws 1.5MB | fT0 2MB | xT1 2MB |
    //                    xT2 2MB | wpart 25.2MB
    char* ws = (char*)d_ws;
    ushort* convwb = (ushort*)ws;
    ushort* msst   = (ushort*)(ws + 6291456);
    ushort* Wsb    = (ushort*)(ws + 6291456 + 8388608);
    ushort* fT0    = (ushort*)(ws + 6291456 + 8388608 + 1572864);
    ushort* xT1    = (ushort*)(ws + 6291456 + 8388608 + 1572864 + 2097152);
    ushort* xT2    = (ushort*)(ws + 6291456 + 8388608 + 1572864 + 2 * 2097152);
    float*  wpart  = (float*)(ws + 6291456 + 8388608 + 1572864 + 3 * 2097152);

    void* args[16] = {
        (void*)&adj, (void*)&feats, (void*)&conv_w, (void*)&conv_b,
        (void*)&gamma, (void*)&beta, (void*)&mean, (void*)&var,
        (void*)&out, (void*)&fT0, (void*)&convwb, (void*)&msst,
        (void*)&wpart, (void*)&Wsb, (void*)&xT1, (void*)&xT2};

    hipError_t e = hipLaunchCooperativeKernel((void*)mega_kernel, dim3(GRID), dim3(256),
                                              args, 0, stream);
    if (e != hipSuccess) {
        // Deterministic fallback: same phase bodies as 6 plain kernels.
        prep_k<<<GRID, 256, 0, stream>>>(adj, feats, conv_w, fT0, convwb, msst);
        weff_k<<<GRID, 256, 0, stream>>>(convwb, msst, wpart);
        reduce_k<<<GRID, 256, 0, stream>>>(wpart, gamma, var, Wsb);
        const ushort* xin[3] = {fT0, xT1, xT2};
        ushort* xout[3] = {xT1, xT2, (ushort*)0};
        for (int l = 0; l < 3; ++l)
            layer_k<<<GRID, 256, 0, stream>>>(
                xin[l], Wsb + (size_t)l * NB * CC * CC,
                conv_b + l * CC, gamma + l * CC, beta + l * CC, mean + l * CC,
                var + l * CC, out + (size_t)l * NB * CC * HWP, xout[l]);
    }
}

// Round 6
// 131.615 us; speedup vs baseline: 2.3501x; 2.3501x over previous
//
#include <hip/hip_runtime.h>
#include <stdint.h>

// N=4 batches, C=256, S=16, H*W=1024, K1=S*C=4096, 3 layers.
#define CC   256
#define SSL  16
#define NB   4
#define HWP  1024
#define K1   4096
#define EPSV 1e-5f

typedef __attribute__((ext_vector_type(8))) short bf16x8;
typedef __attribute__((ext_vector_type(4))) float f32x4;

__device__ __forceinline__ ushort f2bf(float f) {
    uint32_t u = __float_as_uint(f);
    uint32_t r = (u + 0x7FFFu + ((u >> 16) & 1u)) >> 16;   // RNE
    return (ushort)r;
}

// ---------------------------------------------------------------------------
// flags[n][k][b]: 2 = all 16 rows of slice k positive at col b, 1 = any, 0 = none.
__global__ __launch_bounds__(256) void flags_kernel(const float* __restrict__ adj,
                                                    uint8_t* __restrict__ flags) {
    const int nk = blockIdx.x;            // n*16 + k
    const int n = nk >> 4, k = nk & 15;
    const int b = threadIdx.x;
    const float* m = adj + (size_t)n * CC * CC;
    bool allp = true, anyp = false;
#pragma unroll
    for (int i = 0; i < 16; ++i) {
        float v = m[(size_t)(k * 16 + i) * CC + b];
        bool p = v > 0.0f;
        allp = allp && p;
        anyp = anyp || p;
    }
    flags[(size_t)nk * CC + b] = allp ? (uint8_t)2 : (anyp ? (uint8_t)1 : (uint8_t)0);
}

// ---------------------------------------------------------------------------
// conv_w fp32 -> bf16, straight copy. 3*256*4096 elems, 4/thread.
__global__ __launch_bounds__(256) void convw_bf16_kernel(const float* __restrict__ w,
                                                         ushort* __restrict__ wb) {
    const int idx = (blockIdx.x * 256 + threadIdx.x) * 4;
    float4 v = *(const float4*)(w + idx);
    ushort4 o = {f2bf(v.x), f2bf(v.y), f2bf(v.z), f2bf(v.w)};
    *(ushort4*)(wb + idx) = o;
}

// ---------------------------------------------------------------------------
// msst[n][b][k*256+a] = bf16( sel(flag[n,k,b], m[n,a,b]) )  — B^T layout (K-contig).
__global__ __launch_bounds__(256) void msst_kernel(const float* __restrict__ adj,
                                                   const uint8_t* __restrict__ flags,
                                                   ushort* __restrict__ msst) {
    const int n = blockIdx.y;
    const int at = blockIdx.x >> 2, bt = blockIdx.x & 3;
    const int a0 = at * 64, b0 = bt * 64;
    const float* m = adj + (size_t)n * CC * CC;
    __shared__ float Ms[64][68];
    __shared__ uint8_t Fl[16][64];
    const int t = threadIdx.x;
    {
        const int ar = t >> 2, bq = (t & 3) * 16;
        const float* src = m + (size_t)(a0 + ar) * CC + b0 + bq;
#pragma unroll
        for (int i = 0; i < 4; ++i)
            *(float4*)&Ms[ar][bq + i * 4] = *(const float4*)(src + i * 4);
        const int k = t >> 4, b4 = (t & 15) * 4;
        *(uchar4*)&Fl[k][b4] = *(const uchar4*)(flags + (size_t)(n * SSL + k) * CC + b0 + b4);
    }
    __syncthreads();
    const int bl = t >> 2, ac = (t & 3) * 16;
    ushort bx[16], bp[16];
#pragma unroll
    for (int i = 0; i < 16; ++i) {
        float x = Ms[ac + i][bl];
        bx[i] = f2bf(x);
        bp[i] = f2bf(fmaxf(x, 0.0f));
    }
    ushort* dst = msst + ((size_t)(n * CC + b0 + bl)) * K1 + a0 + ac;
#pragma unroll
    for (int k = 0; k < 16; ++k) {
        const uint8_t f = Fl[k][bl];
        ushort* dk = dst + k * CC;
#pragma unroll
        for (int a4 = 0; a4 < 4; ++a4) {
            ushort4 o;
            o.x = (f == 2) ? bx[a4 * 4 + 0] : ((f == 1) ? bp[a4 * 4 + 0] : (ushort)0);
            o.y = (f == 2) ? bx[a4 * 4 + 1] : ((f == 1) ? bp[a4 * 4 + 1] : (ushort)0);
            o.z = (f == 2) ? bx[a4 * 4 + 2] : ((f == 1) ? bp[a4 * 4 + 2] : (ushort)0);
            o.w = (f == 2) ? bx[a4 * 4 + 3] : ((f == 1) ? bp[a4 * 4 + 3] : (ushort)0);
            *(ushort4*)(dk + a4 * 4) = o;
        }
    }
}

// ---------------------------------------------------------------------------
// feats [n][c][p] fp32 -> fT [n][p][c] bf16 (layer-A layout, K=c contiguous).
__global__ __launch_bounds__(256) void featsT_kernel(const float* __restrict__ feats,
                                                     ushort* __restrict__ fT) {
    const int n = blockIdx.y;
    const int ct = blockIdx.x >> 4, pt = blockIdx.x & 15;
    const int c0 = ct * 64, p0 = pt * 64;
    const float* src = feats + ((size_t)n * CC + c0) * HWP + p0;
    __shared__ float Ts[64][68];
    const int t = threadIdx.x;
    const int cr = t >> 2, pq = (t & 3) * 16;
#pragma unroll
    for (int i = 0; i < 4; ++i)
        *(float4*)&Ts[cr][pq + i * 4] = *(const float4*)(src + (size_t)cr * HWP + pq + i * 4);
    __syncthreads();
    const int pl = t >> 2, cc0 = (t & 3) * 16;
    ushort* dst = fT + ((size_t)n * HWP + p0 + pl) * CC + c0 + cc0;
#pragma unroll
    for (int a4 = 0; a4 < 4; ++a4) {
        ushort4 o;
        o.x = f2bf(Ts[cc0 + a4 * 4 + 0][pl]);
        o.y = f2bf(Ts[cc0 + a4 * 4 + 1][pl]);
        o.z = f2bf(Ts[cc0 + a4 * 4 + 2][pl]);
        o.w = f2bf(Ts[cc0 + a4 * 4 + 3][pl]);
        *(ushort4*)(dst + a4 * 4) = o;
    }
}

// ---------------------------------------------------------------------------
// W_eff partial GEMM (bf16 MFMA): R2-exact. 128x128 tile, BK=32, 4 waves x (4x4)
// 16x16x32 MFMA tiles. Grid (4 tiles, 12 ln, 8 sk).
__global__ __launch_bounds__(256) void weff_mfma(const ushort* __restrict__ Aw,
                                                 const ushort* __restrict__ Bm,
                                                 float* __restrict__ wpart) {
    const int tile = blockIdx.x;
    const int ln = blockIdx.y;
    const int sp = blockIdx.z;
    const int l = ln >> 2, n = ln & 3;
    const int trow = (tile >> 1) * 128, tcol = (tile & 1) * 128;
    const ushort* A = Aw + (size_t)l * CC * K1;
    const ushort* B = Bm + (size_t)n * CC * K1;
    __shared__ ushort Al[128][40];
    __shared__ ushort Bl[128][40];
    const int t = threadIdx.x;
    const int wv = t >> 6, L = t & 63;
    const int wr = (wv >> 1) * 64, wc = (wv & 1) * 64;
    const int l16 = L & 15, q = L >> 4;
    const int r0 = t >> 2, kq0 = (t & 3) * 8;
    f32x4 acc[4][4];
#pragma unroll
    for (int i = 0; i < 4; ++i)
#pragma unroll
        for (int j = 0; j < 4; ++j)
            acc[i][j] = (f32x4){0.f, 0.f, 0.f, 0.f};

    const int kbase = sp * 512;
    for (int kt = 0; kt < 16; ++kt) {
        const int kk = kbase + kt * 32;
        int4 a0 = *(const int4*)(A + (size_t)(trow + r0) * K1 + kk + kq0);
        int4 a1 = *(const int4*)(A + (size_t)(trow + 64 + r0) * K1 + kk + kq0);
        int4 b0 = *(const int4*)(B + (size_t)(tcol + r0) * K1 + kk + kq0);
        int4 b1 = *(const int4*)(B + (size_t)(tcol + 64 + r0) * K1 + kk + kq0);
        __syncthreads();
        *(int4*)&Al[r0][kq0] = a0;
        *(int4*)&Al[64 + r0][kq0] = a1;
        *(int4*)&Bl[r0][kq0] = b0;
        *(int4*)&Bl[64 + r0][kq0] = b1;
        __syncthreads();
        bf16x8 af[4], bfr[4];
#pragma unroll
        for (int i = 0; i < 4; ++i)
            af[i] = *(const bf16x8*)&Al[wr + i * 16 + l16][q * 8];
#pragma unroll
        for (int j = 0; j < 4; ++j)
            bfr[j] = *(const bf16x8*)&Bl[wc + j * 16 + l16][q * 8];
#pragma unroll
        for (int i = 0; i < 4; ++i)
#pragma unroll
            for (int j = 0; j < 4; ++j)
                acc[i][j] = __builtin_amdgcn_mfma_f32_16x16x32_bf16(af[i], bfr[j], acc[i][j], 0, 0, 0);
    }

    float* W = wpart + ((size_t)sp * 12 + ln) * (CC * CC);
#pragma unroll
    for (int i = 0; i < 4; ++i)
#pragma unroll
        for (int j = 0; j < 4; ++j) {
            const int o = trow + wr + i * 16 + q * 4;    // D row = quad*4 + reg
            const int b = tcol + wc + j * 16 + l16;      // D col = lane&15
#pragma unroll
            for (int r = 0; r < 4; ++r)
                W[(size_t)(o + r) * CC + b] = acc[i][j][r];
        }
}

// ---------------------------------------------------------------------------
// Sum 8 split-K partials, fold BN row-scale, emit bf16 Ws[l,n][o][b]. R2-exact.
__global__ __launch_bounds__(256) void reduce_kernel(const float* __restrict__ wpart,
                                                     const float* __restrict__ gamma,
                                                     const float* __restrict__ var,
                                                     ushort* __restrict__ Ws) {
    const int idx = (blockIdx.x * 256 + threadIdx.x) * 4;   // over 12*65536
    const int ln = idx >> 16;
    const int l = ln >> 2;
    const int o = (idx >> 8) & 255;
    float4 s = {0.f, 0.f, 0.f, 0.f};
#pragma unroll
    for (int sp = 0; sp < 8; ++sp) {
        float4 v = *(const float4*)(wpart + (size_t)sp * 12 * 65536 + idx);
        s.x += v.x; s.y += v.y; s.z += v.z; s.w += v.w;
    }
    const float sc = gamma[l * CC + o] * rsqrtf(var[l * CC + o] + EPSV);
    ushort4 ob = {f2bf(s.x * sc), f2bf(s.y * sc), f2bf(s.z * sc), f2bf(s.w * sc)};
    *(ushort4*)(Ws + idx) = ob;
}

// ---------------------------------------------------------------------------
// Layer GEMM — ONLY change vs R2: 32x64 tiles, grid 512 = 2 blocks/CU so barrier
// stalls overlap across blocks. 4 waves, each 16p x 32o (2 j-tiles of 16x16).
// Epilogue identical to R2 (direct scattered stores — measured fastest).
__global__ __launch_bounds__(256) void layer_mfma(const ushort* __restrict__ xT,
                                                  const ushort* __restrict__ Wsl,
                                                  const float* __restrict__ convb_l,
                                                  const float* __restrict__ gamma_l,
                                                  const float* __restrict__ beta_l,
                                                  const float* __restrict__ mean_l,
                                                  const float* __restrict__ var_l,
                                                  float* __restrict__ outl,
                                                  ushort* __restrict__ xTn) {
    const int n = blockIdx.y;
    const int pt = blockIdx.x & 31, ot = blockIdx.x >> 5;   // 32 p-tiles x 4 o-tiles
    const ushort* Axt = xT + (size_t)n * HWP * CC + (size_t)pt * 32 * CC;
    const ushort* Bw  = Wsl + (size_t)n * CC * CC + (size_t)ot * 64 * CC;
    __shared__ ushort Al[32][40];
    __shared__ ushort Bl[64][40];
    const int t = threadIdx.x;
    const int wv = t >> 6, L = t & 63;
    const int wr = (wv >> 1) * 16, wc = (wv & 1) * 32;
    const int l16 = L & 15, q = L >> 4;
    const int ra = t >> 3, ka0 = (t & 7) * 4;     // A staging: 32 rows x 32 k, int2
    const int rb = t >> 2, kb0 = (t & 3) * 8;     // B staging: 64 rows x 32 k, int4
    f32x4 acc[2];
    acc[0] = (f32x4){0.f, 0.f, 0.f, 0.f};
    acc[1] = (f32x4){0.f, 0.f, 0.f, 0.f};

    int2 av = *(const int2*)(Axt + (size_t)ra * CC + ka0);
    int4 bv = *(const int4*)(Bw + (size_t)rb * CC + kb0);
    for (int kt = 0; kt < 8; ++kt) {
        __syncthreads();
        *(int2*)&Al[ra][ka0] = av;
        *(int4*)&Bl[rb][kb0] = bv;
        __syncthreads();
        if (kt < 7) {
            const int kk = (kt + 1) * 32;
            av = *(const int2*)(Axt + (size_t)ra * CC + kk + ka0);
            bv = *(const int4*)(Bw + (size_t)rb * CC + kk + kb0);
        }
        bf16x8 af = *(const bf16x8*)&Al[wr + l16][q * 8];
        bf16x8 b0 = *(const bf16x8*)&Bl[wc + l16][q * 8];
        bf16x8 b1 = *(const bf16x8*)&Bl[wc + 16 + l16][q * 8];
        acc[0] = __builtin_amdgcn_mfma_f32_16x16x32_bf16(af, b0, acc[0], 0, 0, 0);
        acc[1] = __builtin_amdgcn_mfma_f32_16x16x32_bf16(af, b1, acc[1], 0, 0, 0);
    }

    float* outn = outl + (size_t)n * CC * HWP;
    ushort* xtn = xTn ? xTn + (size_t)n * HWP * CC : (ushort*)0;
#pragma unroll
    for (int j = 0; j < 2; ++j) {
        const int p = pt * 32 + wr + q * 4;            // D row
        const int o = ot * 64 + wc + j * 16 + l16;     // D col
        const float sc = gamma_l[o] * rsqrtf(var_l[o] + EPSV);
        const float b2 = sc * (convb_l[o] - mean_l[o]) + beta_l[o];
        float v0 = fmaxf(acc[j][0] + b2, 0.f);
        float v1 = fmaxf(acc[j][1] + b2, 0.f);
        float v2 = fmaxf(acc[j][2] + b2, 0.f);
        float v3 = fmaxf(acc[j][3] + b2, 0.f);
        *(float4*)(outn + (size_t)o * HWP + p) = (float4){v0, v1, v2, v3};
        if (xtn) {
            xtn[(size_t)(p + 0) * CC + o] = f2bf(v0);
            xtn[(size_t)(p + 1) * CC + o] = f2bf(v1);
            xtn[(size_t)(p + 2) * CC + o] = f2bf(v2);
            xtn[(size_t)(p + 3) * CC + o] = f2bf(v3);
        }
    }
}

// ---------------------------------------------------------------------------
extern "C" void kernel_launch(void* const* d_in, const int* in_sizes, int n_in,
                              void* d_out, int out_size, void* d_ws, size_t ws_size,
                              hipStream_t stream) {
    const float* feats  = (const float*)d_in[0];
    const float* adj    = (const float*)d_in[1];
    const float* conv_w = (const float*)d_in[2];
    const float* conv_b = (const float*)d_in[3];
    const float* gamma  = (const float*)d_in[4];
    const float* beta   = (const float*)d_in[5];
    const float* mean   = (const float*)d_in[6];
    const float* var    = (const float*)d_in[7];
    float* out = (float*)d_out;

    // ws layout (bytes): R2-exact.
    //   [0, 64K) flags | [+6291456) convwb | [+8388608) msst | [+1572864) Ws
    //   [+2097152) fT0 | [+25165824) wpart fp32 [8][12][o][b] (aliased by xT1..3)
    char* ws = (char*)d_ws;
    uint8_t* flags  = (uint8_t*)ws;
    ushort*  convwb = (ushort*)(ws + 65536);
    ushort*  msst   = (ushort*)(ws + 65536 + 6291456);
    ushort*  Wsb    = (ushort*)(ws + 65536 + 6291456 + 8388608);
    ushort*  fT0    = (ushort*)(ws + 65536 + 6291456 + 8388608 + 1572864);
    float*   wpart  = (float*)(ws + 65536 + 6291456 + 8388608 + 1572864 + 2097152);
    ushort*  xT1    = (ushort*)wpart;                    // safe: wpart consumed by reduce
    ushort*  xT2    = xT1 + (size_t)NB * HWP * CC;
    ushort*  xT3    = xT2 + (size_t)NB * HWP * CC;

    flags_kernel<<<NB * SSL, CC, 0, stream>>>(adj, flags);
    convw_bf16_kernel<<<3072, 256, 0, stream>>>(conv_w, convwb);
    msst_kernel<<<dim3(16, NB), 256, 0, stream>>>(adj, flags, msst);
    featsT_kernel<<<dim3(64, NB), 256, 0, stream>>>(feats, fT0);
    weff_mfma<<<dim3(4, 12, 8), 256, 0, stream>>>(convwb, msst, wpart);
    reduce_kernel<<<768, 256, 0, stream>>>(wpart, gamma, var, Wsb);

    const ushort* xin[3] = {fT0, xT1, xT2};
    ushort* xout[3] = {xT1, xT2, xT3};
    for (int l = 0; l < 3; ++l) {
        layer_mfma<<<dim3(128, NB), 256, 0, stream>>>(
            xin[l], Wsb + (size_t)l * NB * CC * CC,
            conv_b + l * CC, gamma + l * CC, beta + l * CC, mean + l * CC, var + l * CC,
            out + (size_t)l * NB * CC * HWP, xout[l]);
    }
}